// Round 1
// baseline (727.600 us; speedup 1.0000x reference)
//
#include <hip/hip_runtime.h>
#include <hip/hip_bf16.h>

// NestedAttention: B=16,N=1024,D=1024,E=4,H=16,hd=64
// bf16 MFMA pipeline with fp32 accumulate.

typedef __bf16 bf16_t;
typedef __bf16 bf16x8 __attribute__((ext_vector_type(8)));
typedef __bf16 bf16x4 __attribute__((ext_vector_type(4)));
typedef float f32x4 __attribute__((ext_vector_type(4)));

typedef __attribute__((address_space(1))) void gvoid;
typedef __attribute__((address_space(3))) void lvoid;

#define MFMA16(a, b, c) __builtin_amdgcn_mfma_f32_16x16x32_bf16((a), (b), (c), 0, 0, 0)
#define GLOAD_LDS16(gsrc, ldst) \
  __builtin_amdgcn_global_load_lds((gvoid*)(gsrc), (lvoid*)(ldst), 16, 0, 0)

// softmax scale 1/sqrt(64) folded with log2(e) into Q at QKV epilogue
#define QSCALE 0.18033688f

// ---------------------------------------------------------------- prep ----
__global__ __launch_bounds__(256) void prep_tokens(
    const float* __restrict__ x, const int* __restrict__ em,
    bf16_t* __restrict__ xq) {
  const int row = blockIdx.x;                 // token index 0..16383
  const int dt = 128 << em[row];              // nested dim: 128<<e
  const int d = threadIdx.x * 4;
  float4 v = ((const float4*)(x + (size_t)row * 1024))[threadIdx.x];
  const bool keep = d < dt;                   // dt multiple of 128 -> uniform per 4
  bf16x4 o;
  o[0] = (bf16_t)(keep ? v.x : 0.f);
  o[1] = (bf16_t)(keep ? v.y : 0.f);
  o[2] = (bf16_t)(keep ? v.z : 0.f);
  o[3] = (bf16_t)(keep ? v.w : 0.f);
  *((bf16x4*)(xq + (size_t)row * 1024 + d)) = o;
}

__global__ __launch_bounds__(256) void conv_w(
    const float* __restrict__ s, bf16_t* __restrict__ dvec) {
  const int i = blockIdx.x * 256 + threadIdx.x;  // grid sized exactly, no guard
  float4 v = ((const float4*)s)[i];
  bf16x4 o;
  o[0] = (bf16_t)v.x; o[1] = (bf16_t)v.y; o[2] = (bf16_t)v.z; o[3] = (bf16_t)v.w;
  ((bf16x4*)dvec)[i] = o;
}

// ---------------------------------------------------------------- GEMM ----
// C[m,f] = sum_k A[m,k] * Bw[f,k]   (both row-major along k; "B^T" GEMM)
// 128x128 tile, BK=64, 4 waves, 16x16x32 bf16 MFMA (m97 structure).
// EPI 0: QKV epilogue -> scatter q(scaled)/k/vT bf16.  EPI 1: proj epilogue.
template <int EPI>
__global__ __launch_bounds__(256) void gemm128(
    const bf16_t* __restrict__ A, const bf16_t* __restrict__ Bw, int K,
    bf16_t* __restrict__ qo, bf16_t* __restrict__ ko, bf16_t* __restrict__ vto,
    float* __restrict__ yout, const float* __restrict__ bias,
    const int* __restrict__ em) {
  __shared__ bf16_t As[128 * 64];
  __shared__ bf16_t Bs[128 * 64];
  const int tid = threadIdx.x;
  const int lane = tid & 63, w = tid >> 6;
  const int g = lane >> 4, c16 = lane & 15;
  const int rowbase = blockIdx.x * 128;
  const int colbase = blockIdx.y * 128;
  const int wr = (w >> 1) * 64, wc = (w & 1) * 64;

  f32x4 acc[4][4] = {};

  for (int kt = 0; kt < K; kt += 64) {
    // stage A,B tiles: 128 rows x 64 k, linear LDS (dest = wave base + lane*16)
#pragma unroll
    for (int ch = 0; ch < 4; ++ch) {
      const int i = ch * 256 + tid;
      const int r = i >> 3, ko8 = (i & 7) * 8;
      const bf16_t* srcA = A + (size_t)(rowbase + r) * K + kt + ko8;
      const bf16_t* srcB = Bw + (size_t)(colbase + r) * K + kt + ko8;
      GLOAD_LDS16(srcA, As + (ch * 256 + w * 64) * 8);
      GLOAD_LDS16(srcB, Bs + (ch * 256 + w * 64) * 8);
    }
    asm volatile("s_waitcnt vmcnt(0)" ::: "memory");
    __syncthreads();
#pragma unroll
    for (int kk = 0; kk < 2; ++kk) {
      bf16x8 af[4], bf[4];
#pragma unroll
      for (int mi = 0; mi < 4; ++mi)
        af[mi] = *(const bf16x8*)(As + (wr + mi * 16 + c16) * 64 + kk * 32 + g * 8);
#pragma unroll
      for (int ni = 0; ni < 4; ++ni)
        bf[ni] = *(const bf16x8*)(Bs + (wc + ni * 16 + c16) * 64 + kk * 32 + g * 8);
#pragma unroll
      for (int mi = 0; mi < 4; ++mi)
#pragma unroll
        for (int ni = 0; ni < 4; ++ni)
          acc[mi][ni] = MFMA16(af[mi], bf[ni], acc[mi][ni]);
    }
    __syncthreads();
  }

  // C/D layout: col = lane&15, row = (lane>>4)*4 + reg  [m89/m91 verified]
  if constexpr (EPI == 0) {
    const int s = colbase >> 10;  // 0=q,1=k,2=v (uniform per block: 128|1024)
#pragma unroll
    for (int mi = 0; mi < 4; ++mi)
#pragma unroll
      for (int ni = 0; ni < 4; ++ni)
#pragma unroll
        for (int j = 0; j < 4; ++j) {
          const int row = rowbase + wr + mi * 16 + g * 4 + j;  // token
          const int col = colbase + wc + ni * 16 + c16;        // f
          const float v = acc[mi][ni][j];
          const int bb = row >> 10, n = row & 1023;
          const int h = (col >> 6) & 15, e = col & 63;
          const size_t bh = (size_t)(bb * 16 + h);
          if (s == 0)
            qo[(bh * 1024 + n) * 64 + e] = (bf16_t)(v * QSCALE);
          else if (s == 1)
            ko[(bh * 1024 + n) * 64 + e] = (bf16_t)v;
          else
            vto[(bh * 64 + e) * 1024 + n] = (bf16_t)v;  // V transposed
        }
  } else {
#pragma unroll
    for (int mi = 0; mi < 4; ++mi)
#pragma unroll
      for (int j = 0; j < 4; ++j) {
        const int row = rowbase + wr + mi * 16 + g * 4 + j;
        const int dt = 128 << em[row];
#pragma unroll
        for (int ni = 0; ni < 4; ++ni) {
          const int col = colbase + wc + ni * 16 + c16;
          const float v = acc[mi][ni][j] + bias[col];
          yout[(size_t)row * 1024 + col] = (col < dt) ? v : 0.f;
        }
      }
  }
}

// ----------------------------------------------------------- attention ----
// One block = 4 waves; wave handles 16 q rows; block covers 64 q rows of one
// (b,h). Flash-style over 1024 keys in 32-key steps. Q pre-scaled by QSCALE,
// so P = exp2(S - m). All softmax reductions are 16-lane shfl_xor (wave-par).
__global__ __launch_bounds__(256) void attn64(
    const bf16_t* __restrict__ Q, const bf16_t* __restrict__ Kb,
    const bf16_t* __restrict__ VT, bf16_t* __restrict__ X) {
  const int tid = threadIdx.x, w = tid >> 6, l = tid & 63;
  const int g = l >> 4, c16 = l & 15;
  const int bh = blockIdx.y, qt = blockIdx.x;
  const int qbase = qt * 64 + w * 16;

  __shared__ bf16_t P[4][16 * 32];  // per-wave P^T staging (q x key)
  bf16_t* Pw = P[w];

  const bf16_t* Qbh = Q + (size_t)bh * 1024 * 64;
  const bf16_t* Kbh = Kb + (size_t)bh * 1024 * 64;
  const bf16_t* Vbh = VT + (size_t)bh * 64 * 1024;

  // A-frag for QK^T: lane holds Q[row = l&15][k-chunk*32 + g*8 + j]
  const size_t qoff = ((size_t)(qbase + c16)) * 64 + g * 8;
  const bf16x8 qf0 = *(const bf16x8*)(Qbh + qoff);
  const bf16x8 qf1 = *(const bf16x8*)(Qbh + qoff + 32);

  f32x4 O[4] = {};            // O[dchunk][reg]; row=q, col=d
  float m[4], lsum[4];
#pragma unroll
  for (int j = 0; j < 4; ++j) { m[j] = -3.0e38f; lsum[j] = 0.f; }

  for (int kt = 0; kt < 1024; kt += 32) {
    // B-frags for QK^T: lane holds K[key = base + l&15][d = chunk*32 + g*8 + j]
    const bf16_t* K0 = Kbh + (size_t)(kt + c16) * 64 + g * 8;
    const bf16x8 k00 = *(const bf16x8*)(K0);
    const bf16x8 k01 = *(const bf16x8*)(K0 + 32);
    const bf16x8 k10 = *(const bf16x8*)(K0 + 16 * 64);
    const bf16x8 k11 = *(const bf16x8*)(K0 + 16 * 64 + 32);

    f32x4 S0 = {}, S1 = {};
    S0 = MFMA16(qf0, k00, S0);
    S0 = MFMA16(qf1, k01, S0);
    S1 = MFMA16(qf0, k10, S1);
    S1 = MFMA16(qf1, k11, S1);

    float corr[4];
#pragma unroll
    for (int j = 0; j < 4; ++j) {
      float t = fmaxf(S0[j], S1[j]);
      t = fmaxf(t, __shfl_xor(t, 1));
      t = fmaxf(t, __shfl_xor(t, 2));
      t = fmaxf(t, __shfl_xor(t, 4));
      t = fmaxf(t, __shfl_xor(t, 8));
      const float mn = fmaxf(m[j], t);
      const float p0 = exp2f(S0[j] - mn);
      const float p1 = exp2f(S1[j] - mn);
      float r = p0 + p1;
      r += __shfl_xor(r, 1);
      r += __shfl_xor(r, 2);
      r += __shfl_xor(r, 4);
      r += __shfl_xor(r, 8);
      const float cr = exp2f(m[j] - mn);
      corr[j] = cr;
      lsum[j] = lsum[j] * cr + r;
      m[j] = mn;
      // stash P (row = q = g*4+j, col = key) for the LDS transpose
      Pw[(g * 4 + j) * 32 + c16] = (bf16_t)p0;
      Pw[(g * 4 + j) * 32 + 16 + c16] = (bf16_t)p1;
    }
#pragma unroll
    for (int ni = 0; ni < 4; ++ni) {
      O[ni][0] *= corr[0]; O[ni][1] *= corr[1];
      O[ni][2] *= corr[2]; O[ni][3] *= corr[3];
    }
    // per-wave private LDS: wait our own ds_writes, then read transposed
    asm volatile("s_waitcnt lgkmcnt(0)" ::: "memory");
    const bf16x8 pa = *(const bf16x8*)(Pw + c16 * 32 + g * 8);  // A[q=l&15][kk=g*8+j]

    // B-frags for PV from V^T: lane holds V[key = kt + g*8 + j][d = ni*16 + c16]
    const bf16_t* V0 = Vbh + (size_t)c16 * 1024 + kt + g * 8;
    const bf16x8 v0 = *(const bf16x8*)(V0);
    const bf16x8 v1 = *(const bf16x8*)(V0 + 16 * 1024);
    const bf16x8 v2 = *(const bf16x8*)(V0 + 32 * 1024);
    const bf16x8 v3 = *(const bf16x8*)(V0 + 48 * 1024);
    O[0] = MFMA16(pa, v0, O[0]);
    O[1] = MFMA16(pa, v1, O[1]);
    O[2] = MFMA16(pa, v2, O[2]);
    O[3] = MFMA16(pa, v3, O[3]);
  }

  float rl[4];
#pragma unroll
  for (int j = 0; j < 4; ++j) rl[j] = 1.f / lsum[j];
  const int bb = bh >> 4, h = bh & 15;
#pragma unroll
  for (int ni = 0; ni < 4; ++ni)
#pragma unroll
    for (int j = 0; j < 4; ++j) {
      const int qrow = qbase + g * 4 + j;
      X[((size_t)(bb * 1024 + qrow)) * 1024 + h * 64 + ni * 16 + c16] =
          (bf16_t)(O[ni][j] * rl[j]);
    }
}

// --------------------------------------------------------------- launch ----
extern "C" void kernel_launch(void* const* d_in, const int* in_sizes, int n_in,
                              void* d_out, int out_size, void* d_ws,
                              size_t ws_size, hipStream_t stream) {
  const float* x = (const float*)d_in[0];
  const int* em = (const int*)d_in[1];
  const float* qkvw = (const float*)d_in[2];
  const float* projw = (const float*)d_in[3];
  const float* projb = (const float*)d_in[4];
  float* out = (float*)d_out;

  char* ws = (char*)d_ws;
  size_t off = 0;
  bf16_t* xin = (bf16_t*)(ws + off); off += (size_t)16384 * 1024 * 2;  // reused as Xattn
  bf16_t* wq  = (bf16_t*)(ws + off); off += (size_t)3072 * 1024 * 2;
  bf16_t* wp  = (bf16_t*)(ws + off); off += (size_t)1024 * 1024 * 2;
  bf16_t* Qb  = (bf16_t*)(ws + off); off += (size_t)256 * 1024 * 64 * 2;
  bf16_t* Kb  = (bf16_t*)(ws + off); off += (size_t)256 * 1024 * 64 * 2;
  bf16_t* VTb = (bf16_t*)(ws + off); off += (size_t)256 * 64 * 1024 * 2;
  // total ~143 MB

  prep_tokens<<<16384, 256, 0, stream>>>(x, em, xin);
  conv_w<<<3072, 256, 0, stream>>>(qkvw, wq);   // 3072*1024/4 / 256
  conv_w<<<1024, 256, 0, stream>>>(projw, wp);  // 1024*1024/4 / 256

  // QKV: M=16384, N=3072, K=1024
  gemm128<0><<<dim3(128, 24), 256, 0, stream>>>(
      xin, wq, 1024, Qb, Kb, VTb, nullptr, nullptr, nullptr);

  // attention: 16 q-tiles x 256 (b,h); writes Xattn into xin region
  attn64<<<dim3(16, 256), 256, 0, stream>>>(Qb, Kb, VTb, xin);

  // proj: M=16384, N=1024, K=1024 (+bias, nested output mask)
  gemm128<1><<<dim3(128, 8), 256, 0, stream>>>(
      xin, wp, 1024, nullptr, nullptr, nullptr, out, projb, em);
}

// Round 2
// 373.839 us; speedup vs baseline: 1.9463x; 1.9463x over previous
//
#include <hip/hip_runtime.h>
#include <hip/hip_bf16.h>

// NestedAttention: B=16,N=1024,D=1024,E=4,H=16,hd=64
// bf16 MFMA pipeline with fp32 accumulate.

typedef __bf16 bf16_t;
typedef __bf16 bf16x8 __attribute__((ext_vector_type(8)));
typedef __bf16 bf16x4 __attribute__((ext_vector_type(4)));
typedef float f32x4 __attribute__((ext_vector_type(4)));
typedef float f32x16 __attribute__((ext_vector_type(16)));
typedef int i32x4 __attribute__((ext_vector_type(4)));

typedef __attribute__((address_space(1))) void gvoid;
typedef __attribute__((address_space(3))) void lvoid;

#define MFMA16(a, b, c) __builtin_amdgcn_mfma_f32_16x16x32_bf16((a), (b), (c), 0, 0, 0)
#define MFMA32(a, b, c) __builtin_amdgcn_mfma_f32_32x32x16_bf16((a), (b), (c), 0, 0, 0)
#define GLOAD_LDS16(gsrc, ldst) \
  __builtin_amdgcn_global_load_lds((gvoid*)(gsrc), (lvoid*)(ldst), 16, 0, 0)

// softmax scale 1/sqrt(64) folded with log2(e) into Q at QKV epilogue
#define QSCALE 0.18033688f

__device__ __forceinline__ unsigned cvtpk(float lo, float hi) {
  unsigned r;
  asm("v_cvt_pk_bf16_f32 %0, %1, %2" : "=v"(r) : "v"(lo), "v"(hi));
  return r;
}
__device__ __forceinline__ void pl32swap(unsigned& x, unsigned& y) {
  asm("v_permlane32_swap_b32 %0, %1" : "+v"(x), "+v"(y));
}

// ---------------------------------------------------------------- prep ----
__global__ __launch_bounds__(256) void prep_tokens(
    const float* __restrict__ x, const int* __restrict__ em,
    bf16_t* __restrict__ xq) {
  const int row = blockIdx.x;                 // token index 0..16383
  const int dt = 128 << em[row];              // nested dim: 128<<e
  const int d = threadIdx.x * 4;
  float4 v = ((const float4*)(x + (size_t)row * 1024))[threadIdx.x];
  const bool keep = d < dt;                   // dt multiple of 128 -> uniform per 4
  bf16x4 o;
  o[0] = (bf16_t)(keep ? v.x : 0.f);
  o[1] = (bf16_t)(keep ? v.y : 0.f);
  o[2] = (bf16_t)(keep ? v.z : 0.f);
  o[3] = (bf16_t)(keep ? v.w : 0.f);
  *((bf16x4*)(xq + (size_t)row * 1024 + d)) = o;
}

__global__ __launch_bounds__(256) void conv_w(
    const float* __restrict__ s, bf16_t* __restrict__ dvec) {
  const int i = blockIdx.x * 256 + threadIdx.x;  // grid sized exactly, no guard
  float4 v = ((const float4*)s)[i];
  bf16x4 o;
  o[0] = (bf16_t)v.x; o[1] = (bf16_t)v.y; o[2] = (bf16_t)v.z; o[3] = (bf16_t)v.w;
  ((bf16x4*)dvec)[i] = o;
}

// ---------------------------------------------------------------- GEMM ----
// C[m,f] = sum_k A[m,k] * Bw[f,k]   (both row-major along k; "B^T" GEMM)
// 128x128 tile, BK=64, 4 waves, 16x16x32 bf16 MFMA (m97 structure).
// EPI 0: QKV epilogue -> scatter q(scaled)/k/vT bf16.  EPI 1: proj epilogue.
template <int EPI>
__global__ __launch_bounds__(256) void gemm128(
    const bf16_t* __restrict__ A, const bf16_t* __restrict__ Bw, int K,
    bf16_t* __restrict__ qo, bf16_t* __restrict__ ko, bf16_t* __restrict__ vto,
    float* __restrict__ yout, const float* __restrict__ bias,
    const int* __restrict__ em) {
  __shared__ bf16_t As[128 * 64];
  __shared__ bf16_t Bs[128 * 64];
  const int tid = threadIdx.x;
  const int lane = tid & 63, w = tid >> 6;
  const int g = lane >> 4, c16 = lane & 15;
  const int rowbase = blockIdx.x * 128;
  const int colbase = blockIdx.y * 128;
  const int wr = (w >> 1) * 64, wc = (w & 1) * 64;

  f32x4 acc[4][4] = {};

  for (int kt = 0; kt < K; kt += 64) {
#pragma unroll
    for (int ch = 0; ch < 4; ++ch) {
      const int i = ch * 256 + tid;
      const int r = i >> 3, ko8 = (i & 7) * 8;
      const bf16_t* srcA = A + (size_t)(rowbase + r) * K + kt + ko8;
      const bf16_t* srcB = Bw + (size_t)(colbase + r) * K + kt + ko8;
      GLOAD_LDS16(srcA, As + (ch * 256 + w * 64) * 8);
      GLOAD_LDS16(srcB, Bs + (ch * 256 + w * 64) * 8);
    }
    asm volatile("s_waitcnt vmcnt(0)" ::: "memory");
    __syncthreads();
#pragma unroll
    for (int kk = 0; kk < 2; ++kk) {
      bf16x8 af[4], bfr[4];
#pragma unroll
      for (int mi = 0; mi < 4; ++mi)
        af[mi] = *(const bf16x8*)(As + (wr + mi * 16 + c16) * 64 + kk * 32 + g * 8);
#pragma unroll
      for (int ni = 0; ni < 4; ++ni)
        bfr[ni] = *(const bf16x8*)(Bs + (wc + ni * 16 + c16) * 64 + kk * 32 + g * 8);
#pragma unroll
      for (int mi = 0; mi < 4; ++mi)
#pragma unroll
        for (int ni = 0; ni < 4; ++ni)
          acc[mi][ni] = MFMA16(af[mi], bfr[ni], acc[mi][ni]);
    }
    __syncthreads();
  }

  // C/D layout: col = lane&15, row = (lane>>4)*4 + reg  [m89/m91 verified]
  if constexpr (EPI == 0) {
    const int s = colbase >> 10;  // 0=q,1=k,2=v (uniform per block: 128|1024)
#pragma unroll
    for (int mi = 0; mi < 4; ++mi)
#pragma unroll
      for (int ni = 0; ni < 4; ++ni)
#pragma unroll
        for (int j = 0; j < 4; ++j) {
          const int row = rowbase + wr + mi * 16 + g * 4 + j;  // token
          const int col = colbase + wc + ni * 16 + c16;        // f
          const float v = acc[mi][ni][j];
          const int bb = row >> 10, n = row & 1023;
          const int h = (col >> 6) & 15, e = col & 63;
          const size_t bh = (size_t)(bb * 16 + h);
          if (s == 0)
            qo[(bh * 1024 + n) * 64 + e] = (bf16_t)(v * QSCALE);
          else if (s == 1)
            ko[(bh * 1024 + n) * 64 + e] = (bf16_t)v;
          else
            vto[(bh * 64 + e) * 1024 + n] = (bf16_t)v;  // V transposed
        }
  } else {
#pragma unroll
    for (int mi = 0; mi < 4; ++mi)
#pragma unroll
      for (int j = 0; j < 4; ++j) {
        const int row = rowbase + wr + mi * 16 + g * 4 + j;
        const int dt = 128 << em[row];
#pragma unroll
        for (int ni = 0; ni < 4; ++ni) {
          const int col = colbase + wc + ni * 16 + c16;
          const float v = acc[mi][ni][j] + bias[col];
          yout[(size_t)row * 1024 + col] = (col < dt) ? v : 0.f;
        }
      }
  }
}

// ----------------------------------------------------------- attention ----
// 8 waves x 32 q-rows = 256 q rows / block. KVBLK=64 double-buffered in LDS
// (K row-major [64key][64d], V^T [64d][64key], both XOR-swizzled).
// Swapped QK^T: S = mfma32(Kfrag, Qfrag) -> lane holds P-row slice for
// q = lane&31 in registers; softmax fully in-register; P->bf16 via
// cvt_pk + permlane32_swap feeds PV's A operand directly.
__global__ __launch_bounds__(512, 2) void attn256(
    const bf16_t* __restrict__ Q, const bf16_t* __restrict__ Kb,
    const bf16_t* __restrict__ VT, bf16_t* __restrict__ X) {
  __shared__ bf16_t Klds[2][4096];
  __shared__ bf16_t Vlds[2][4096];
  const int tid = threadIdx.x;
  const int w = tid >> 6, lane = tid & 63;
  const int k32 = lane & 31, q5 = lane >> 5;
  const int bh = blockIdx.y;
  const int qbase = blockIdx.x * 256 + w * 32;

  const bf16_t* Qbh = Q + (size_t)bh * 65536;
  const bf16_t* Kbh = Kb + (size_t)bh * 65536;
  const bf16_t* Vbh = VT + (size_t)bh * 65536;

  // staging: thread t stages 16B of K-tile and 16B of VT-tile, linear LDS
  // dest, inverse-swizzled global source (rule #21).
  const int trow = tid >> 3;
  const int tslot = (tid & 7) ^ (trow & 7);
  const bf16_t* kg = Kbh + (size_t)trow * 64 + tslot * 8;
  const bf16_t* vg = Vbh + (size_t)trow * 1024 + tslot * 8;

  // Q B-frags: lane holds Q[qbase + (lane&31)][kc*16 + (lane>>5)*8 + j]
  bf16x8 qf[4];
#pragma unroll
  for (int kc = 0; kc < 4; ++kc)
    qf[kc] = *(const bf16x8*)(Qbh + (size_t)(qbase + k32) * 64 + kc * 16 + q5 * 8);
  // Force Q-load completion here so the waitcnt pass never re-waits in-loop.
  asm volatile("" ::"v"(qf[0]), "v"(qf[1]), "v"(qf[2]), "v"(qf[3]));

  // swizzled LDS read offsets (same form for K and VT tiles)
  const int rbase = k32 * 128 + q5 * 16;
  const int rswz = (k32 & 7) << 4;

  f32x16 O0 = {}, O1 = {};
  float m = -3.0e38f, lsum = 0.f;

  GLOAD_LDS16(kg, (bf16_t*)Klds[0] + tid * 8);
  GLOAD_LDS16(vg, (bf16_t*)Vlds[0] + tid * 8);

  for (int step = 0; step < 16; ++step) {
    const int buf = step & 1;
    if (step < 15) {
      GLOAD_LDS16(kg + (step + 1) * 4096, (bf16_t*)Klds[buf ^ 1] + tid * 8);
      GLOAD_LDS16(vg + (step + 1) * 64, (bf16_t*)Vlds[buf ^ 1] + tid * 8);
      asm volatile("s_waitcnt vmcnt(2)" ::: "memory");
    } else {
      asm volatile("s_waitcnt vmcnt(0)" ::: "memory");
    }
    __builtin_amdgcn_s_barrier();

    const char* Kl = (const char*)Klds[buf];
    const char* Vl = (const char*)Vlds[buf];

    // S tiles: S0 = keys 0..31, S1 = keys 32..63 (swapped operands)
    f32x16 S0 = {}, S1 = {};
#pragma unroll
    for (int kc = 0; kc < 4; ++kc) {
      const int off = (rbase + kc * 32) ^ rswz;
      bf16x8 kf0 = *(const bf16x8*)(Kl + off);
      bf16x8 kf1 = *(const bf16x8*)(Kl + off + 4096);
      S0 = MFMA32(kf0, qf[kc], S0);
      S1 = MFMA32(kf1, qf[kc], S1);
    }

    // in-register softmax for q = lane&31 (keys split across lane^32)
    float pm = fmaxf(S0[0], S1[0]);
#pragma unroll
    for (int r = 1; r < 16; ++r) pm = fmaxf(pm, fmaxf(S0[r], S1[r]));
    pm = fmaxf(pm, __shfl_xor(pm, 32));
    if (__any(pm > m + 8.f)) {           // defer-max, THR=8 (log2 domain)
      const float mnew = fmaxf(m, pm);
      const float corr = __builtin_amdgcn_exp2f(m - mnew);
      m = mnew;
      lsum *= corr;
      const int ci = __builtin_bit_cast(int, corr);
#pragma unroll
      for (int r = 0; r < 16; ++r) {     // corr broadcast into O layout
        const int qsel = (r & 3) + 8 * (r >> 2) + 4 * q5;
        const float cr = __builtin_bit_cast(
            float, __builtin_amdgcn_ds_bpermute(qsel << 2, ci));
        O0[r] *= cr;
        O1[r] *= cr;
      }
    }
    float ps = 0.f;
#pragma unroll
    for (int r = 0; r < 16; ++r) {
      float p = __builtin_amdgcn_exp2f(S0[r] - m);
      ps += p; S0[r] = p;
      p = __builtin_amdgcn_exp2f(S1[r] - m);
      ps += p; S1[r] = p;
    }
    lsum += ps;

    // P -> bf16 A-frags (cvt_pk + permlane32_swap), PV MFMAs
#define MAKE_PA(PV, B0, PA)                            \
  {                                                    \
    unsigned a_ = cvtpk(PV[B0 + 0], PV[B0 + 1]);       \
    unsigned b_ = cvtpk(PV[B0 + 2], PV[B0 + 3]);       \
    unsigned c_ = cvtpk(PV[B0 + 4], PV[B0 + 5]);       \
    unsigned d_ = cvtpk(PV[B0 + 6], PV[B0 + 7]);       \
    pl32swap(a_, c_);                                  \
    pl32swap(b_, d_);                                  \
    i32x4 wv_;                                         \
    wv_[0] = a_; wv_[1] = b_; wv_[2] = c_; wv_[3] = d_; \
    PA = __builtin_bit_cast(bf16x8, wv_);              \
  }
#define PV_STEP(PV, B0, KS)                                       \
  {                                                               \
    bf16x8 pa;                                                    \
    MAKE_PA(PV, B0, pa);                                          \
    const int voff = (rbase + (KS) * 32) ^ rswz;                  \
    bf16x8 vf0 = *(const bf16x8*)(Vl + voff);                     \
    bf16x8 vf1 = *(const bf16x8*)(Vl + voff + 4096);              \
    O0 = MFMA32(pa, vf0, O0);                                     \
    O1 = MFMA32(pa, vf1, O1);                                     \
  }
    PV_STEP(S0, 0, 0)
    PV_STEP(S0, 8, 1)
    PV_STEP(S1, 0, 2)
    PV_STEP(S1, 8, 3)

    __builtin_amdgcn_s_barrier();
  }

  // epilogue: normalize and store
  lsum += __shfl_xor(lsum, 32);
  const float rinv = 1.f / lsum;
  const int ri = __builtin_bit_cast(int, rinv);
  const int bb = bh >> 4, h = bh & 15;
  bf16_t* Xb = X + (size_t)bb * 1024 * 1024 + h * 64;
#pragma unroll
  for (int r = 0; r < 16; ++r) {
    const int qsel = (r & 3) + 8 * (r >> 2) + 4 * q5;  // O row within wave
    const float rv = __builtin_bit_cast(
        float, __builtin_amdgcn_ds_bpermute(qsel << 2, ri));
    const size_t rowoff = (size_t)(qbase + qsel) * 1024;
    Xb[rowoff + k32] = (bf16_t)(O0[r] * rv);
    Xb[rowoff + 32 + k32] = (bf16_t)(O1[r] * rv);
  }
}

// --------------------------------------------------------------- launch ----
extern "C" void kernel_launch(void* const* d_in, const int* in_sizes, int n_in,
                              void* d_out, int out_size, void* d_ws,
                              size_t ws_size, hipStream_t stream) {
  const float* x = (const float*)d_in[0];
  const int* em = (const int*)d_in[1];
  const float* qkvw = (const float*)d_in[2];
  const float* projw = (const float*)d_in[3];
  const float* projb = (const float*)d_in[4];
  float* out = (float*)d_out;

  char* ws = (char*)d_ws;
  size_t off = 0;
  bf16_t* xin = (bf16_t*)(ws + off); off += (size_t)16384 * 1024 * 2;  // reused as Xattn
  bf16_t* wq  = (bf16_t*)(ws + off); off += (size_t)3072 * 1024 * 2;
  bf16_t* wp  = (bf16_t*)(ws + off); off += (size_t)1024 * 1024 * 2;
  bf16_t* Qb  = (bf16_t*)(ws + off); off += (size_t)256 * 1024 * 64 * 2;
  bf16_t* Kb  = (bf16_t*)(ws + off); off += (size_t)256 * 1024 * 64 * 2;
  bf16_t* VTb = (bf16_t*)(ws + off); off += (size_t)256 * 64 * 1024 * 2;

  prep_tokens<<<16384, 256, 0, stream>>>(x, em, xin);
  conv_w<<<3072, 256, 0, stream>>>(qkvw, wq);
  conv_w<<<1024, 256, 0, stream>>>(projw, wp);

  // QKV: M=16384, N=3072, K=1024
  gemm128<0><<<dim3(128, 24), 256, 0, stream>>>(
      xin, wq, 1024, Qb, Kb, VTb, nullptr, nullptr, nullptr);

  // attention: 4 q-tiles x 256 (b,h); writes Xattn into xin region
  attn256<<<dim3(4, 256), 512, 0, stream>>>(Qb, Kb, VTb, xin);

  // proj: M=16384, N=1024, K=1024 (+bias, nested output mask)
  gemm128<1><<<dim3(128, 8), 256, 0, stream>>>(
      xin, wp, 1024, nullptr, nullptr, nullptr, out, projb, em);
}

// Round 3
// 356.692 us; speedup vs baseline: 2.0399x; 1.0481x over previous
//
#include <hip/hip_runtime.h>
#include <hip/hip_bf16.h>

// NestedAttention: B=16,N=1024,D=1024,E=4,H=16,hd=64
// bf16 MFMA pipeline with fp32 accumulate.

typedef __bf16 bf16_t;
typedef __bf16 bf16x8 __attribute__((ext_vector_type(8)));
typedef __bf16 bf16x4 __attribute__((ext_vector_type(4)));
typedef float f32x4 __attribute__((ext_vector_type(4)));
typedef float f32x16 __attribute__((ext_vector_type(16)));
typedef int i32x4 __attribute__((ext_vector_type(4)));

typedef __attribute__((address_space(1))) void gvoid;
typedef __attribute__((address_space(3))) void lvoid;

#define MFMA16(a, b, c) __builtin_amdgcn_mfma_f32_16x16x32_bf16((a), (b), (c), 0, 0, 0)
#define MFMA32(a, b, c) __builtin_amdgcn_mfma_f32_32x32x16_bf16((a), (b), (c), 0, 0, 0)
#define GLOAD_LDS16(gsrc, ldst) \
  __builtin_amdgcn_global_load_lds((gvoid*)(gsrc), (lvoid*)(ldst), 16, 0, 0)

// softmax scale 1/sqrt(64) folded with log2(e) into Q at QKV epilogue
#define QSCALE 0.18033688f

__device__ __forceinline__ unsigned cvtpk(float lo, float hi) {
  unsigned r;
  asm("v_cvt_pk_bf16_f32 %0, %1, %2" : "=v"(r) : "v"(lo), "v"(hi));
  return r;
}
__device__ __forceinline__ void pl32swap(unsigned& x, unsigned& y) {
  asm("v_permlane32_swap_b32 %0, %1" : "+v"(x), "+v"(y));
}

// ---------------------------------------------------------------- prep ----
__global__ __launch_bounds__(256) void prep_tokens(
    const float* __restrict__ x, const int* __restrict__ em,
    bf16_t* __restrict__ xq) {
  const int row = blockIdx.x;                 // token index 0..16383
  const int dt = 128 << em[row];              // nested dim: 128<<e
  const int d = threadIdx.x * 4;
  float4 v = ((const float4*)(x + (size_t)row * 1024))[threadIdx.x];
  const bool keep = d < dt;                   // dt multiple of 128 -> uniform per 4
  bf16x4 o;
  o[0] = (bf16_t)(keep ? v.x : 0.f);
  o[1] = (bf16_t)(keep ? v.y : 0.f);
  o[2] = (bf16_t)(keep ? v.z : 0.f);
  o[3] = (bf16_t)(keep ? v.w : 0.f);
  *((bf16x4*)(xq + (size_t)row * 1024 + d)) = o;
}

__global__ __launch_bounds__(256) void conv_w(
    const float* __restrict__ s, bf16_t* __restrict__ dvec) {
  const int i = blockIdx.x * 256 + threadIdx.x;  // grid sized exactly, no guard
  float4 v = ((const float4*)s)[i];
  bf16x4 o;
  o[0] = (bf16_t)v.x; o[1] = (bf16_t)v.y; o[2] = (bf16_t)v.z; o[3] = (bf16_t)v.w;
  ((bf16x4*)dvec)[i] = o;
}

// ---------------------------------------------------------------- GEMM ----
// C[m,f] = sum_k A[m,k] * Bw[f,k]  ("B^T" GEMM). 256x256 tile, BK=64,
// 8 waves (2M x 4N), per-wave 128x64, 4 phases/K-tile of 16 MFMA each,
// double-buffered swizzled LDS (T2), per-phase barriers + setprio (T5),
// XCD-chunked col-major block order (T1).
// EPI 0: QKV epilogue -> scatter q(scaled)/k/vT bf16.  EPI 1: proj epilogue.
template <int EPI>
__global__ __launch_bounds__(512, 2) void gemm256(
    const bf16_t* __restrict__ A, const bf16_t* __restrict__ Bw, int K,
    bf16_t* __restrict__ qo, bf16_t* __restrict__ ko, bf16_t* __restrict__ vto,
    float* __restrict__ yout, const float* __restrict__ bias,
    const int* __restrict__ em) {
  __shared__ bf16_t lds[2][32768];  // per buf: A 32KB + B 32KB (chunk-swizzled)
  const int tid = threadIdx.x;
  const int lane = tid & 63, w = tid >> 6;
  const int wm = w >> 2, wn = w & 3;
  const int g = lane >> 4, c16 = lane & 15;

  // XCD-bijective swizzle over col-major logical order (nwg % 8 == 0)
  const int nwg = gridDim.x;
  const int lb = ((int)blockIdx.x & 7) * (nwg >> 3) + ((int)blockIdx.x >> 3);
  const int rowbase = (lb & 63) * 256;  // M = 16384 -> 64 row blocks
  const int colbase = (lb >> 6) * 256;

  // staging: thread stages 8x16B chunks/K-tile; linear LDS dest, inverse-
  // swizzled global source (chunk col = (tid&7) ^ (row&7); rule #21).
  const int trow = tid >> 3;
  const int scol = (((tid & 7) ^ (trow & 7)) << 3);
  const bf16_t* pa = A + (size_t)(rowbase + trow) * K + scol;
  const bf16_t* pb = Bw + (size_t)(colbase + trow) * K + scol;

#define STAGE(j, koff, dst)                                       \
  GLOAD_LDS16(((j) < 4 ? pa + (size_t)((j) * 64) * K              \
                       : pb + (size_t)(((j) - 4) * 64) * K) +     \
                  (koff),                                         \
              (dst) + ((j) * 512 + tid) * 8)

  // swizzled fragment read: row R, k-chunk (kk*4+g), elem = R*64 + swz*8
#define LDFRAG(base, R, kk)            \
  (*(const bf16x8*)((base) + (size_t)(R) * 64 + \
                    (((((kk) << 2) + g) ^ (c16 & 7)) << 3)))

  f32x4 acc[8][4] = {};
  bf16x8 af[4][2], b0[2][2], b1[2][2];

  // prologue: stage K-tile 0
  STAGE(0, 0, lds[0]); STAGE(1, 0, lds[0]); STAGE(2, 0, lds[0]);
  STAGE(3, 0, lds[0]); STAGE(4, 0, lds[0]); STAGE(5, 0, lds[0]);
  STAGE(6, 0, lds[0]); STAGE(7, 0, lds[0]);
  asm volatile("s_waitcnt vmcnt(0)" ::: "memory");
  __builtin_amdgcn_s_barrier();

  const int NT = K >> 6;
  for (int t = 0; t < NT; ++t) {
    const bf16_t* Lb = lds[t & 1];
    const bf16_t* LbB = Lb + 16384;
    bf16_t* Sd = lds[(t + 1) & 1];
    const int koff = (t + 1) << 6;
    const bool pf = t < NT - 1;

    // ---- phase 0: rows 0-63 x cols 0-31
#pragma unroll
    for (int mi = 0; mi < 4; ++mi)
#pragma unroll
      for (int kk = 0; kk < 2; ++kk)
        af[mi][kk] = LDFRAG(Lb, wm * 128 + mi * 16 + c16, kk);
#pragma unroll
    for (int ni = 0; ni < 2; ++ni)
#pragma unroll
      for (int kk = 0; kk < 2; ++kk)
        b0[ni][kk] = LDFRAG(LbB, wn * 64 + ni * 16 + c16, kk);
    if (pf) { STAGE(0, koff, Sd); STAGE(1, koff, Sd); STAGE(2, koff, Sd); }
    __builtin_amdgcn_s_barrier();
    __builtin_amdgcn_s_setprio(1);
#pragma unroll
    for (int mi = 0; mi < 4; ++mi)
#pragma unroll
      for (int ni = 0; ni < 2; ++ni)
#pragma unroll
        for (int kk = 0; kk < 2; ++kk)
          acc[mi][ni] = MFMA16(af[mi][kk], b0[ni][kk], acc[mi][ni]);
    __builtin_amdgcn_s_setprio(0);
    __builtin_amdgcn_s_barrier();

    // ---- phase 1: rows 0-63 x cols 32-63 (A held)
#pragma unroll
    for (int ni = 0; ni < 2; ++ni)
#pragma unroll
      for (int kk = 0; kk < 2; ++kk)
        b1[ni][kk] = LDFRAG(LbB, wn * 64 + (ni + 2) * 16 + c16, kk);
    if (pf) { STAGE(3, koff, Sd); STAGE(4, koff, Sd); STAGE(5, koff, Sd); }
    __builtin_amdgcn_s_barrier();
    __builtin_amdgcn_s_setprio(1);
#pragma unroll
    for (int mi = 0; mi < 4; ++mi)
#pragma unroll
      for (int ni = 0; ni < 2; ++ni)
#pragma unroll
        for (int kk = 0; kk < 2; ++kk)
          acc[mi][ni + 2] = MFMA16(af[mi][kk], b1[ni][kk], acc[mi][ni + 2]);
    __builtin_amdgcn_s_setprio(0);
    __builtin_amdgcn_s_barrier();

    // ---- phase 2: rows 64-127 x cols 0-31 (B0 held)
#pragma unroll
    for (int mi = 0; mi < 4; ++mi)
#pragma unroll
      for (int kk = 0; kk < 2; ++kk)
        af[mi][kk] = LDFRAG(Lb, wm * 128 + (mi + 4) * 16 + c16, kk);
    if (pf) { STAGE(6, koff, Sd); STAGE(7, koff, Sd); }
    __builtin_amdgcn_s_barrier();
    __builtin_amdgcn_s_setprio(1);
#pragma unroll
    for (int mi = 0; mi < 4; ++mi)
#pragma unroll
      for (int ni = 0; ni < 2; ++ni)
#pragma unroll
        for (int kk = 0; kk < 2; ++kk)
          acc[mi + 4][ni] = MFMA16(af[mi][kk], b0[ni][kk], acc[mi + 4][ni]);
    __builtin_amdgcn_s_setprio(0);
    __builtin_amdgcn_s_barrier();

    // ---- phase 3: rows 64-127 x cols 32-63 (A,B1 held); tile-boundary drain
    __builtin_amdgcn_s_setprio(1);
#pragma unroll
    for (int mi = 0; mi < 4; ++mi)
#pragma unroll
      for (int ni = 0; ni < 2; ++ni)
#pragma unroll
        for (int kk = 0; kk < 2; ++kk)
          acc[mi + 4][ni + 2] = MFMA16(af[mi][kk], b1[ni][kk], acc[mi + 4][ni + 2]);
    __builtin_amdgcn_s_setprio(0);
    asm volatile("s_waitcnt vmcnt(0)" ::: "memory");
    __builtin_amdgcn_s_barrier();
  }

  // C/D layout: col = lane&15, row = (lane>>4)*4 + reg  [m89/m91 verified]
  if constexpr (EPI == 0) {
    const int s = colbase >> 10;  // 0=q,1=k,2=v (uniform per block: 256|1024)
#pragma unroll
    for (int mi = 0; mi < 8; ++mi)
#pragma unroll
      for (int ni = 0; ni < 4; ++ni)
#pragma unroll
        for (int j = 0; j < 4; ++j) {
          const int row = rowbase + wm * 128 + mi * 16 + g * 4 + j;  // token
          const int col = colbase + wn * 64 + ni * 16 + c16;         // f
          const float v = acc[mi][ni][j];
          const int bb = row >> 10, n = row & 1023;
          const int h = (col >> 6) & 15, e = col & 63;
          const size_t bh = (size_t)(bb * 16 + h);
          if (s == 0)
            qo[(bh * 1024 + n) * 64 + e] = (bf16_t)(v * QSCALE);
          else if (s == 1)
            ko[(bh * 1024 + n) * 64 + e] = (bf16_t)v;
          else
            vto[(bh * 64 + e) * 1024 + n] = (bf16_t)v;  // V transposed
        }
  } else {
#pragma unroll
    for (int mi = 0; mi < 8; ++mi)
#pragma unroll
      for (int j = 0; j < 4; ++j) {
        const int row = rowbase + wm * 128 + mi * 16 + g * 4 + j;
        const int dt = 128 << em[row];
#pragma unroll
        for (int ni = 0; ni < 4; ++ni) {
          const int col = colbase + wn * 64 + ni * 16 + c16;
          const float v = acc[mi][ni][j] + bias[col];
          yout[(size_t)row * 1024 + col] = (col < dt) ? v : 0.f;
        }
      }
  }
#undef STAGE
#undef LDFRAG
}

// ----------------------------------------------------------- attention ----
// 8 waves x 32 q-rows = 256 q rows / block. KVBLK=64 double-buffered in LDS
// (K row-major [64key][64d], V^T [64d][64key], both XOR-swizzled).
// Swapped QK^T: S = mfma32(Kfrag, Qfrag) -> lane holds P-row slice for
// q = lane&31 in registers; softmax fully in-register; P->bf16 via
// cvt_pk + permlane32_swap feeds PV's A operand directly.
__global__ __launch_bounds__(512, 2) void attn256(
    const bf16_t* __restrict__ Q, const bf16_t* __restrict__ Kb,
    const bf16_t* __restrict__ VT, bf16_t* __restrict__ X) {
  __shared__ bf16_t Klds[2][4096];
  __shared__ bf16_t Vlds[2][4096];
  const int tid = threadIdx.x;
  const int w = tid >> 6, lane = tid & 63;
  const int k32 = lane & 31, q5 = lane >> 5;
  const int bh = blockIdx.y;
  const int qbase = blockIdx.x * 256 + w * 32;

  const bf16_t* Qbh = Q + (size_t)bh * 65536;
  const bf16_t* Kbh = Kb + (size_t)bh * 65536;
  const bf16_t* Vbh = VT + (size_t)bh * 65536;

  const int trow = tid >> 3;
  const int tslot = (tid & 7) ^ (trow & 7);
  const bf16_t* kg = Kbh + (size_t)trow * 64 + tslot * 8;
  const bf16_t* vg = Vbh + (size_t)trow * 1024 + tslot * 8;

  bf16x8 qf[4];
#pragma unroll
  for (int kc = 0; kc < 4; ++kc)
    qf[kc] = *(const bf16x8*)(Qbh + (size_t)(qbase + k32) * 64 + kc * 16 + q5 * 8);
  asm volatile("" ::"v"(qf[0]), "v"(qf[1]), "v"(qf[2]), "v"(qf[3]));

  const int rbase = k32 * 128 + q5 * 16;
  const int rswz = (k32 & 7) << 4;

  f32x16 O0 = {}, O1 = {};
  float m = -3.0e38f, lsum = 0.f;

  GLOAD_LDS16(kg, (bf16_t*)Klds[0] + tid * 8);
  GLOAD_LDS16(vg, (bf16_t*)Vlds[0] + tid * 8);

  for (int step = 0; step < 16; ++step) {
    const int buf = step & 1;
    if (step < 15) {
      GLOAD_LDS16(kg + (step + 1) * 4096, (bf16_t*)Klds[buf ^ 1] + tid * 8);
      GLOAD_LDS16(vg + (step + 1) * 64, (bf16_t*)Vlds[buf ^ 1] + tid * 8);
      asm volatile("s_waitcnt vmcnt(2)" ::: "memory");
    } else {
      asm volatile("s_waitcnt vmcnt(0)" ::: "memory");
    }
    __builtin_amdgcn_s_barrier();

    const char* Kl = (const char*)Klds[buf];
    const char* Vl = (const char*)Vlds[buf];

    f32x16 S0 = {}, S1 = {};
#pragma unroll
    for (int kc = 0; kc < 4; ++kc) {
      const int off = (rbase + kc * 32) ^ rswz;
      bf16x8 kf0 = *(const bf16x8*)(Kl + off);
      bf16x8 kf1 = *(const bf16x8*)(Kl + off + 4096);
      S0 = MFMA32(kf0, qf[kc], S0);
      S1 = MFMA32(kf1, qf[kc], S1);
    }

    float pm = fmaxf(S0[0], S1[0]);
#pragma unroll
    for (int r = 1; r < 16; ++r) pm = fmaxf(pm, fmaxf(S0[r], S1[r]));
    pm = fmaxf(pm, __shfl_xor(pm, 32));
    if (__any(pm > m + 8.f)) {           // defer-max, THR=8 (log2 domain)
      const float mnew = fmaxf(m, pm);
      const float corr = __builtin_amdgcn_exp2f(m - mnew);
      m = mnew;
      lsum *= corr;
      const int ci = __builtin_bit_cast(int, corr);
#pragma unroll
      for (int r = 0; r < 16; ++r) {
        const int qsel = (r & 3) + 8 * (r >> 2) + 4 * q5;
        const float cr = __builtin_bit_cast(
            float, __builtin_amdgcn_ds_bpermute(qsel << 2, ci));
        O0[r] *= cr;
        O1[r] *= cr;
      }
    }
    float ps = 0.f;
#pragma unroll
    for (int r = 0; r < 16; ++r) {
      float p = __builtin_amdgcn_exp2f(S0[r] - m);
      ps += p; S0[r] = p;
      p = __builtin_amdgcn_exp2f(S1[r] - m);
      ps += p; S1[r] = p;
    }
    lsum += ps;

#define MAKE_PA(PV, B0, PA)                            \
  {                                                    \
    unsigned a_ = cvtpk(PV[B0 + 0], PV[B0 + 1]);       \
    unsigned b_ = cvtpk(PV[B0 + 2], PV[B0 + 3]);       \
    unsigned c_ = cvtpk(PV[B0 + 4], PV[B0 + 5]);       \
    unsigned d_ = cvtpk(PV[B0 + 6], PV[B0 + 7]);       \
    pl32swap(a_, c_);                                  \
    pl32swap(b_, d_);                                  \
    i32x4 wv_;                                         \
    wv_[0] = a_; wv_[1] = b_; wv_[2] = c_; wv_[3] = d_; \
    PA = __builtin_bit_cast(bf16x8, wv_);              \
  }
#define PV_STEP(PV, B0, KS)                                       \
  {                                                               \
    bf16x8 pa;                                                    \
    MAKE_PA(PV, B0, pa);                                          \
    const int voff = (rbase + (KS) * 32) ^ rswz;                  \
    bf16x8 vf0 = *(const bf16x8*)(Vl + voff);                     \
    bf16x8 vf1 = *(const bf16x8*)(Vl + voff + 4096);              \
    O0 = MFMA32(pa, vf0, O0);                                     \
    O1 = MFMA32(pa, vf1, O1);                                     \
  }
    PV_STEP(S0, 0, 0)
    PV_STEP(S0, 8, 1)
    PV_STEP(S1, 0, 2)
    PV_STEP(S1, 8, 3)

    __builtin_amdgcn_s_barrier();
  }

  lsum += __shfl_xor(lsum, 32);
  const float rinv = 1.f / lsum;
  const int ri = __builtin_bit_cast(int, rinv);
  const int bb = bh >> 4, h = bh & 15;
  bf16_t* Xb = X + (size_t)bb * 1024 * 1024 + h * 64;
#pragma unroll
  for (int r = 0; r < 16; ++r) {
    const int qsel = (r & 3) + 8 * (r >> 2) + 4 * q5;
    const float rv = __builtin_bit_cast(
        float, __builtin_amdgcn_ds_bpermute(qsel << 2, ri));
    const size_t rowoff = (size_t)(qbase + qsel) * 1024;
    Xb[rowoff + k32] = (bf16_t)(O0[r] * rv);
    Xb[rowoff + 32 + k32] = (bf16_t)(O1[r] * rv);
  }
}

// --------------------------------------------------------------- launch ----
extern "C" void kernel_launch(void* const* d_in, const int* in_sizes, int n_in,
                              void* d_out, int out_size, void* d_ws,
                              size_t ws_size, hipStream_t stream) {
  const float* x = (const float*)d_in[0];
  const int* em = (const int*)d_in[1];
  const float* qkvw = (const float*)d_in[2];
  const float* projw = (const float*)d_in[3];
  const float* projb = (const float*)d_in[4];
  float* out = (float*)d_out;

  char* ws = (char*)d_ws;
  size_t off = 0;
  bf16_t* xin = (bf16_t*)(ws + off); off += (size_t)16384 * 1024 * 2;  // reused as Xattn
  bf16_t* wq  = (bf16_t*)(ws + off); off += (size_t)3072 * 1024 * 2;
  bf16_t* wp  = (bf16_t*)(ws + off); off += (size_t)1024 * 1024 * 2;
  bf16_t* Qb  = (bf16_t*)(ws + off); off += (size_t)256 * 1024 * 64 * 2;
  bf16_t* Kb  = (bf16_t*)(ws + off); off += (size_t)256 * 1024 * 64 * 2;
  bf16_t* VTb = (bf16_t*)(ws + off); off += (size_t)256 * 64 * 1024 * 2;

  prep_tokens<<<16384, 256, 0, stream>>>(x, em, xin);
  conv_w<<<3072, 256, 0, stream>>>(qkvw, wq);
  conv_w<<<1024, 256, 0, stream>>>(projw, wp);

  // QKV: M=16384, N=3072, K=1024 -> 64x12 = 768 blocks (col-major + XCD swz)
  gemm256<0><<<768, 512, 0, stream>>>(
      xin, wq, 1024, Qb, Kb, VTb, nullptr, nullptr, nullptr);

  // attention: 4 q-tiles x 256 (b,h); writes Xattn into xin region
  attn256<<<dim3(4, 256), 512, 0, stream>>>(Qb, Kb, VTb, xin);

  // proj: M=16384, N=1024, K=1024 -> 64x4 = 256 blocks
  gemm256<1><<<256, 512, 0, stream>>>(
      xin, wp, 1024, nullptr, nullptr, nullptr, out, projb, em);
}

// Round 4
// 333.626 us; speedup vs baseline: 2.1809x; 1.0691x over previous
//
#include <hip/hip_runtime.h>
#include <hip/hip_bf16.h>

// NestedAttention: B=16,N=1024,D=1024,E=4,H=16,hd=64
// bf16 MFMA pipeline with fp32 accumulate.

typedef __bf16 bf16_t;
typedef __bf16 bf16x8 __attribute__((ext_vector_type(8)));
typedef __bf16 bf16x4 __attribute__((ext_vector_type(4)));
typedef float f32x4 __attribute__((ext_vector_type(4)));
typedef float f32x16 __attribute__((ext_vector_type(16)));
typedef int i32x4 __attribute__((ext_vector_type(4)));

typedef __attribute__((address_space(1))) void gvoid;
typedef __attribute__((address_space(3))) void lvoid;

#define MFMA16(a, b, c) __builtin_amdgcn_mfma_f32_16x16x32_bf16((a), (b), (c), 0, 0, 0)
#define MFMA32(a, b, c) __builtin_amdgcn_mfma_f32_32x32x16_bf16((a), (b), (c), 0, 0, 0)
#define GLOAD_LDS16(gsrc, ldst) \
  __builtin_amdgcn_global_load_lds((gvoid*)(gsrc), (lvoid*)(ldst), 16, 0, 0)

// softmax scale 1/sqrt(64) folded with log2(e) into Q at QKV epilogue
#define QSCALE 0.18033688f

__device__ __forceinline__ unsigned cvtpk(float lo, float hi) {
  unsigned r;
  asm("v_cvt_pk_bf16_f32 %0, %1, %2" : "=v"(r) : "v"(lo), "v"(hi));
  return r;
}
__device__ __forceinline__ void pl32swap(unsigned& x, unsigned& y) {
  asm("v_permlane32_swap_b32 %0, %1" : "+v"(x), "+v"(y));
}

// ---------------------------------------------------------------- prep ----
__global__ __launch_bounds__(256) void prep_tokens(
    const float* __restrict__ x, const int* __restrict__ em,
    bf16_t* __restrict__ xq) {
  const int row = blockIdx.x;                 // token index 0..16383
  const int dt = 128 << em[row];              // nested dim: 128<<e
  const int d = threadIdx.x * 4;
  float4 v = ((const float4*)(x + (size_t)row * 1024))[threadIdx.x];
  const bool keep = d < dt;                   // dt multiple of 128 -> uniform per 4
  bf16x4 o;
  o[0] = (bf16_t)(keep ? v.x : 0.f);
  o[1] = (bf16_t)(keep ? v.y : 0.f);
  o[2] = (bf16_t)(keep ? v.z : 0.f);
  o[3] = (bf16_t)(keep ? v.w : 0.f);
  *((bf16x4*)(xq + (size_t)row * 1024 + d)) = o;
}

__global__ __launch_bounds__(256) void conv_w(
    const float* __restrict__ s, bf16_t* __restrict__ dvec) {
  const int i = blockIdx.x * 256 + threadIdx.x;  // grid sized exactly, no guard
  float4 v = ((const float4*)s)[i];
  bf16x4 o;
  o[0] = (bf16_t)v.x; o[1] = (bf16_t)v.y; o[2] = (bf16_t)v.z; o[3] = (bf16_t)v.w;
  ((bf16x4*)dvec)[i] = o;
}

// ---------------------------------------------------------------- GEMM ----
// C[m,f] = sum_k A[m,k] * Bw[f,k]  ("B^T" GEMM). 256x256 tile, BK=64,
// 8 waves (2M x 4N), per-wave 128x64, 4 phases/K-tile of 16 MFMA each.
// T2 chunk-swizzled LDS; T4 counted vmcnt: phase 3 stages tile t+2 into the
// buffer just vacated (buf[t&1]) and waits vmcnt(8) -> only tile t+1's loads
// (issued one full tile earlier) must land; load pipe never drains.
// T1: XCD-bijective chunks, row-major within chunk (A-panel read by exactly
// one XCD; B is small+shared).
// EPI 0: QKV epilogue -> scatter q(scaled)/k/vT bf16.  EPI 1: proj epilogue.
template <int EPI, int NCOL>
__global__ __launch_bounds__(512, 2) void gemm256(
    const bf16_t* __restrict__ A, const bf16_t* __restrict__ Bw, int K,
    bf16_t* __restrict__ qo, bf16_t* __restrict__ ko, bf16_t* __restrict__ vto,
    float* __restrict__ yout, const float* __restrict__ bias,
    const int* __restrict__ em) {
  __shared__ bf16_t lds[2][32768];  // per buf: A 32KB + B 32KB (chunk-swizzled)
  const int tid = threadIdx.x;
  const int lane = tid & 63, w = tid >> 6;
  const int wm = w >> 2, wn = w & 3;
  const int g = lane >> 4, c16 = lane & 15;

  // XCD-bijective swizzle (nwg % 8 == 0), row-major within each XCD chunk
  const int nwg = gridDim.x;
  const int lb = ((int)blockIdx.x & 7) * (nwg >> 3) + ((int)blockIdx.x >> 3);
  const int rowbase = (lb / NCOL) * 256;
  const int colbase = (lb % NCOL) * 256;

  // staging: thread stages 8x16B chunks/K-tile; linear LDS dest, inverse-
  // swizzled global source (chunk col = (tid&7) ^ (row&7); rule #21).
  const int trow = tid >> 3;
  const int scol = (((tid & 7) ^ (trow & 7)) << 3);
  const bf16_t* pa = A + (size_t)(rowbase + trow) * K + scol;
  const bf16_t* pb = Bw + (size_t)(colbase + trow) * K + scol;

#define STAGE(j, koff, dst)                                       \
  GLOAD_LDS16(((j) < 4 ? pa + (size_t)((j) * 64) * K              \
                       : pb + (size_t)(((j) - 4) * 64) * K) +     \
                  (koff),                                         \
              (dst) + ((j) * 512 + tid) * 8)

  // swizzled fragment read: row R, k-chunk (kk*4+g), elem = R*64 + swz*8
#define LDFRAG(base, R, kk)            \
  (*(const bf16x8*)((base) + (size_t)(R) * 64 + \
                    (((((kk) << 2) + g) ^ (c16 & 7)) << 3)))

  f32x4 acc[8][4] = {};
  bf16x8 af[4][2], b0[2][2], b1[2][2];

  // prologue: stage K-tiles 0 and 1; wait only for tile 0 (vmcnt(8))
#pragma unroll
  for (int j = 0; j < 8; ++j) STAGE(j, 0, (bf16_t*)lds[0]);
#pragma unroll
  for (int j = 0; j < 8; ++j) STAGE(j, 64, (bf16_t*)lds[1]);
  asm volatile("s_waitcnt vmcnt(8)" ::: "memory");
  __builtin_amdgcn_s_barrier();

  const int NT = K >> 6;
  for (int t = 0; t < NT; ++t) {
    const bf16_t* Lb = lds[t & 1];
    const bf16_t* LbB = Lb + 16384;
    bf16_t* Sd = (bf16_t*)lds[t & 1];  // tile t+2 -> buffer vacated this tile
    const int koff = (t + 2) << 6;
    const bool pf = (t + 2) < NT;

    // ---- phase 0: rows 0-63 x cols 0-31
#pragma unroll
    for (int mi = 0; mi < 4; ++mi)
#pragma unroll
      for (int kk = 0; kk < 2; ++kk)
        af[mi][kk] = LDFRAG(Lb, wm * 128 + mi * 16 + c16, kk);
#pragma unroll
    for (int ni = 0; ni < 2; ++ni)
#pragma unroll
      for (int kk = 0; kk < 2; ++kk)
        b0[ni][kk] = LDFRAG(LbB, wn * 64 + ni * 16 + c16, kk);
    __builtin_amdgcn_s_barrier();
    __builtin_amdgcn_s_setprio(1);
#pragma unroll
    for (int mi = 0; mi < 4; ++mi)
#pragma unroll
      for (int ni = 0; ni < 2; ++ni)
#pragma unroll
        for (int kk = 0; kk < 2; ++kk)
          acc[mi][ni] = MFMA16(af[mi][kk], b0[ni][kk], acc[mi][ni]);
    __builtin_amdgcn_s_setprio(0);
    __builtin_amdgcn_s_barrier();

    // ---- phase 1: rows 0-63 x cols 32-63 (A held)
#pragma unroll
    for (int ni = 0; ni < 2; ++ni)
#pragma unroll
      for (int kk = 0; kk < 2; ++kk)
        b1[ni][kk] = LDFRAG(LbB, wn * 64 + (ni + 2) * 16 + c16, kk);
    __builtin_amdgcn_s_barrier();
    __builtin_amdgcn_s_setprio(1);
#pragma unroll
    for (int mi = 0; mi < 4; ++mi)
#pragma unroll
      for (int ni = 0; ni < 2; ++ni)
#pragma unroll
        for (int kk = 0; kk < 2; ++kk)
          acc[mi][ni + 2] = MFMA16(af[mi][kk], b1[ni][kk], acc[mi][ni + 2]);
    __builtin_amdgcn_s_setprio(0);
    __builtin_amdgcn_s_barrier();

    // ---- phase 2: rows 64-127 x cols 0-31 (B0 held)
#pragma unroll
    for (int mi = 0; mi < 4; ++mi)
#pragma unroll
      for (int kk = 0; kk < 2; ++kk)
        af[mi][kk] = LDFRAG(Lb, wm * 128 + (mi + 4) * 16 + c16, kk);
    __builtin_amdgcn_s_barrier();
    __builtin_amdgcn_s_setprio(1);
#pragma unroll
    for (int mi = 0; mi < 4; ++mi)
#pragma unroll
      for (int ni = 0; ni < 2; ++ni)
#pragma unroll
        for (int kk = 0; kk < 2; ++kk)
          acc[mi + 4][ni] = MFMA16(af[mi][kk], b0[ni][kk], acc[mi + 4][ni]);
    __builtin_amdgcn_s_setprio(0);
    __builtin_amdgcn_s_barrier();

    // ---- phase 3: rows 64-127 x cols 32-63 (A,B1 held, reg-only MFMA);
    // stage tile t+2 into the now-dead buffer, counted wait for tile t+1.
    if (pf) {
#pragma unroll
      for (int j = 0; j < 8; ++j) STAGE(j, koff, Sd);
    }
    __builtin_amdgcn_s_setprio(1);
#pragma unroll
    for (int mi = 0; mi < 4; ++mi)
#pragma unroll
      for (int ni = 0; ni < 2; ++ni)
#pragma unroll
        for (int kk = 0; kk < 2; ++kk)
          acc[mi + 4][ni + 2] = MFMA16(af[mi][kk], b1[ni][kk], acc[mi + 4][ni + 2]);
    __builtin_amdgcn_s_setprio(0);
    if (pf) {
      asm volatile("s_waitcnt vmcnt(8)" ::: "memory");
    } else {
      asm volatile("s_waitcnt vmcnt(0)" ::: "memory");
    }
    __builtin_amdgcn_s_barrier();
  }

  // C/D layout: col = lane&15, row = (lane>>4)*4 + reg  [m89/m91 verified]
  if constexpr (EPI == 0) {
    const int s = colbase >> 10;  // 0=q,1=k,2=v (uniform per block: 256|1024)
#pragma unroll
    for (int mi = 0; mi < 8; ++mi)
#pragma unroll
      for (int ni = 0; ni < 4; ++ni)
#pragma unroll
        for (int j = 0; j < 4; ++j) {
          const int row = rowbase + wm * 128 + mi * 16 + g * 4 + j;  // token
          const int col = colbase + wn * 64 + ni * 16 + c16;         // f
          const float v = acc[mi][ni][j];
          const int bb = row >> 10, n = row & 1023;
          const int h = (col >> 6) & 15, e = col & 63;
          const size_t bh = (size_t)(bb * 16 + h);
          if (s == 0)
            qo[(bh * 1024 + n) * 64 + e] = (bf16_t)(v * QSCALE);
          else if (s == 1)
            ko[(bh * 1024 + n) * 64 + e] = (bf16_t)v;
          else
            vto[(bh * 64 + e) * 1024 + n] = (bf16_t)v;  // V transposed
        }
  } else {
#pragma unroll
    for (int mi = 0; mi < 8; ++mi)
#pragma unroll
      for (int j = 0; j < 4; ++j) {
        const int row = rowbase + wm * 128 + mi * 16 + g * 4 + j;
        const int dt = 128 << em[row];
#pragma unroll
        for (int ni = 0; ni < 4; ++ni) {
          const int col = colbase + wn * 64 + ni * 16 + c16;
          const float v = acc[mi][ni][j] + bias[col];
          yout[(size_t)row * 1024 + col] = (col < dt) ? v : 0.f;
        }
      }
  }
#undef STAGE
#undef LDFRAG
}

// ----------------------------------------------------------- attention ----
// 8 waves x 32 q-rows = 256 q rows / block. KVBLK=64 double-buffered in LDS
// (K row-major [64key][64d], V^T [64d][64key], both XOR-swizzled).
// Swapped QK^T: S = mfma32(Kfrag, Qfrag) -> lane holds P-row slice for
// q = lane&31 in registers; softmax fully in-register; P->bf16 via
// cvt_pk + permlane32_swap feeds PV's A operand directly.
__global__ __launch_bounds__(512, 2) void attn256(
    const bf16_t* __restrict__ Q, const bf16_t* __restrict__ Kb,
    const bf16_t* __restrict__ VT, bf16_t* __restrict__ X) {
  __shared__ bf16_t Klds[2][4096];
  __shared__ bf16_t Vlds[2][4096];
  const int tid = threadIdx.x;
  const int w = tid >> 6, lane = tid & 63;
  const int k32 = lane & 31, q5 = lane >> 5;
  const int bh = blockIdx.y;
  const int qbase = blockIdx.x * 256 + w * 32;

  const bf16_t* Qbh = Q + (size_t)bh * 65536;
  const bf16_t* Kbh = Kb + (size_t)bh * 65536;
  const bf16_t* Vbh = VT + (size_t)bh * 65536;

  const int trow = tid >> 3;
  const int tslot = (tid & 7) ^ (trow & 7);
  const bf16_t* kg = Kbh + (size_t)trow * 64 + tslot * 8;
  const bf16_t* vg = Vbh + (size_t)trow * 1024 + tslot * 8;

  bf16x8 qf[4];
#pragma unroll
  for (int kc = 0; kc < 4; ++kc)
    qf[kc] = *(const bf16x8*)(Qbh + (size_t)(qbase + k32) * 64 + kc * 16 + q5 * 8);
  asm volatile("" ::"v"(qf[0]), "v"(qf[1]), "v"(qf[2]), "v"(qf[3]));

  const int rbase = k32 * 128 + q5 * 16;
  const int rswz = (k32 & 7) << 4;

  f32x16 O0 = {}, O1 = {};
  float m = -3.0e38f, lsum = 0.f;

  GLOAD_LDS16(kg, (bf16_t*)Klds[0] + tid * 8);
  GLOAD_LDS16(vg, (bf16_t*)Vlds[0] + tid * 8);

  for (int step = 0; step < 16; ++step) {
    const int buf = step & 1;
    if (step < 15) {
      GLOAD_LDS16(kg + (step + 1) * 4096, (bf16_t*)Klds[buf ^ 1] + tid * 8);
      GLOAD_LDS16(vg + (step + 1) * 64, (bf16_t*)Vlds[buf ^ 1] + tid * 8);
      asm volatile("s_waitcnt vmcnt(2)" ::: "memory");
    } else {
      asm volatile("s_waitcnt vmcnt(0)" ::: "memory");
    }
    __builtin_amdgcn_s_barrier();

    const char* Kl = (const char*)Klds[buf];
    const char* Vl = (const char*)Vlds[buf];

    f32x16 S0 = {}, S1 = {};
#pragma unroll
    for (int kc = 0; kc < 4; ++kc) {
      const int off = (rbase + kc * 32) ^ rswz;
      bf16x8 kf0 = *(const bf16x8*)(Kl + off);
      bf16x8 kf1 = *(const bf16x8*)(Kl + off + 4096);
      S0 = MFMA32(kf0, qf[kc], S0);
      S1 = MFMA32(kf1, qf[kc], S1);
    }

    float pm = fmaxf(S0[0], S1[0]);
#pragma unroll
    for (int r = 1; r < 16; ++r) pm = fmaxf(pm, fmaxf(S0[r], S1[r]));
    pm = fmaxf(pm, __shfl_xor(pm, 32));
    if (__any(pm > m + 8.f)) {           // defer-max, THR=8 (log2 domain)
      const float mnew = fmaxf(m, pm);
      const float corr = __builtin_amdgcn_exp2f(m - mnew);
      m = mnew;
      lsum *= corr;
      const int ci = __builtin_bit_cast(int, corr);
#pragma unroll
      for (int r = 0; r < 16; ++r) {
        const int qsel = (r & 3) + 8 * (r >> 2) + 4 * q5;
        const float cr = __builtin_bit_cast(
            float, __builtin_amdgcn_ds_bpermute(qsel << 2, ci));
        O0[r] *= cr;
        O1[r] *= cr;
      }
    }
    float ps = 0.f;
#pragma unroll
    for (int r = 0; r < 16; ++r) {
      float p = __builtin_amdgcn_exp2f(S0[r] - m);
      ps += p; S0[r] = p;
      p = __builtin_amdgcn_exp2f(S1[r] - m);
      ps += p; S1[r] = p;
    }
    lsum += ps;

#define MAKE_PA(PV, B0, PA)                            \
  {                                                    \
    unsigned a_ = cvtpk(PV[B0 + 0], PV[B0 + 1]);       \
    unsigned b_ = cvtpk(PV[B0 + 2], PV[B0 + 3]);       \
    unsigned c_ = cvtpk(PV[B0 + 4], PV[B0 + 5]);       \
    unsigned d_ = cvtpk(PV[B0 + 6], PV[B0 + 7]);       \
    pl32swap(a_, c_);                                  \
    pl32swap(b_, d_);                                  \
    i32x4 wv_;                                         \
    wv_[0] = a_; wv_[1] = b_; wv_[2] = c_; wv_[3] = d_; \
    PA = __builtin_bit_cast(bf16x8, wv_);              \
  }
#define PV_STEP(PV, B0, KS)                                       \
  {                                                               \
    bf16x8 pa;                                                    \
    MAKE_PA(PV, B0, pa);                                          \
    const int voff = (rbase + (KS) * 32) ^ rswz;                  \
    bf16x8 vf0 = *(const bf16x8*)(Vl + voff);                     \
    bf16x8 vf1 = *(const bf16x8*)(Vl + voff + 4096);              \
    O0 = MFMA32(pa, vf0, O0);                                     \
    O1 = MFMA32(pa, vf1, O1);                                     \
  }
    PV_STEP(S0, 0, 0)
    PV_STEP(S0, 8, 1)
    PV_STEP(S1, 0, 2)
    PV_STEP(S1, 8, 3)

    __builtin_amdgcn_s_barrier();
  }

  lsum += __shfl_xor(lsum, 32);
  const float rinv = 1.f / lsum;
  const int ri = __builtin_bit_cast(int, rinv);
  const int bb = bh >> 4, h = bh & 15;
  bf16_t* Xb = X + (size_t)bb * 1024 * 1024 + h * 64;
#pragma unroll
  for (int r = 0; r < 16; ++r) {
    const int qsel = (r & 3) + 8 * (r >> 2) + 4 * q5;
    const float rv = __builtin_bit_cast(
        float, __builtin_amdgcn_ds_bpermute(qsel << 2, ri));
    const size_t rowoff = (size_t)(qbase + qsel) * 1024;
    Xb[rowoff + k32] = (bf16_t)(O0[r] * rv);
    Xb[rowoff + 32 + k32] = (bf16_t)(O1[r] * rv);
  }
}

// --------------------------------------------------------------- launch ----
extern "C" void kernel_launch(void* const* d_in, const int* in_sizes, int n_in,
                              void* d_out, int out_size, void* d_ws,
                              size_t ws_size, hipStream_t stream) {
  const float* x = (const float*)d_in[0];
  const int* em = (const int*)d_in[1];
  const float* qkvw = (const float*)d_in[2];
  const float* projw = (const float*)d_in[3];
  const float* projb = (const float*)d_in[4];
  float* out = (float*)d_out;

  char* ws = (char*)d_ws;
  size_t off = 0;
  bf16_t* xin = (bf16_t*)(ws + off); off += (size_t)16384 * 1024 * 2;  // reused as Xattn
  bf16_t* wq  = (bf16_t*)(ws + off); off += (size_t)3072 * 1024 * 2;
  bf16_t* wp  = (bf16_t*)(ws + off); off += (size_t)1024 * 1024 * 2;
  bf16_t* Qb  = (bf16_t*)(ws + off); off += (size_t)256 * 1024 * 64 * 2;
  bf16_t* Kb  = (bf16_t*)(ws + off); off += (size_t)256 * 1024 * 64 * 2;
  bf16_t* VTb = (bf16_t*)(ws + off); off += (size_t)256 * 64 * 1024 * 2;

  prep_tokens<<<16384, 256, 0, stream>>>(x, em, xin);
  conv_w<<<3072, 256, 0, stream>>>(qkvw, wq);
  conv_w<<<1024, 256, 0, stream>>>(projw, wp);

  // QKV: M=16384, N=3072, K=1024 -> 64x12 = 768 blocks
  gemm256<0, 12><<<768, 512, 0, stream>>>(
      xin, wq, 1024, Qb, Kb, VTb, nullptr, nullptr, nullptr);

  // attention: 4 q-tiles x 256 (b,h); writes Xattn into xin region
  attn256<<<dim3(4, 256), 512, 0, stream>>>(Qb, Kb, VTb, xin);

  // proj: M=16384, N=1024, K=1024 -> 64x4 = 256 blocks
  gemm256<1, 4><<<256, 512, 0, stream>>>(
      xin, wp, 1024, nullptr, nullptr, nullptr, out, projb, em);
}

// Round 5
// 320.350 us; speedup vs baseline: 2.2713x; 1.0414x over previous
//
#include <hip/hip_runtime.h>
#include <hip/hip_bf16.h>

// NestedAttention: B=16,N=1024,D=1024,E=4,H=16,hd=64
// bf16 MFMA pipeline with fp32 accumulate.

typedef __bf16 bf16_t;
typedef __bf16 bf16x8 __attribute__((ext_vector_type(8)));
typedef __bf16 bf16x4 __attribute__((ext_vector_type(4)));
typedef float f32x4 __attribute__((ext_vector_type(4)));
typedef float f32x16 __attribute__((ext_vector_type(16)));
typedef int i32x4 __attribute__((ext_vector_type(4)));

typedef __attribute__((address_space(1))) void gvoid;
typedef __attribute__((address_space(3))) void lvoid;

#define MFMA16(a, b, c) __builtin_amdgcn_mfma_f32_16x16x32_bf16((a), (b), (c), 0, 0, 0)
#define MFMA32(a, b, c) __builtin_amdgcn_mfma_f32_32x32x16_bf16((a), (b), (c), 0, 0, 0)
#define GLOAD_LDS16(gsrc, ldst) \
  __builtin_amdgcn_global_load_lds((gvoid*)(gsrc), (lvoid*)(ldst), 16, 0, 0)

// softmax scale 1/sqrt(64) folded with log2(e) into Q at QKV epilogue
#define QSCALE 0.18033688f

__device__ __forceinline__ unsigned cvtpk(float lo, float hi) {
  unsigned r;
  asm("v_cvt_pk_bf16_f32 %0, %1, %2" : "=v"(r) : "v"(lo), "v"(hi));
  return r;
}
__device__ __forceinline__ void pl32swap(unsigned& x, unsigned& y) {
  asm("v_permlane32_swap_b32 %0, %1" : "+v"(x), "+v"(y));
}

// ---------------------------------------------------------------- prep ----
__global__ __launch_bounds__(256) void prep_tokens(
    const float* __restrict__ x, const int* __restrict__ em,
    bf16_t* __restrict__ xq) {
  const int row = blockIdx.x;                 // token index 0..16383
  const int dt = 128 << em[row];              // nested dim: 128<<e
  const int d = threadIdx.x * 4;
  float4 v = ((const float4*)(x + (size_t)row * 1024))[threadIdx.x];
  const bool keep = d < dt;                   // dt multiple of 128 -> uniform per 4
  bf16x4 o;
  o[0] = (bf16_t)(keep ? v.x : 0.f);
  o[1] = (bf16_t)(keep ? v.y : 0.f);
  o[2] = (bf16_t)(keep ? v.z : 0.f);
  o[3] = (bf16_t)(keep ? v.w : 0.f);
  *((bf16x4*)(xq + (size_t)row * 1024 + d)) = o;
}

__global__ __launch_bounds__(256) void conv_w(
    const float* __restrict__ s, bf16_t* __restrict__ dvec) {
  const int i = blockIdx.x * 256 + threadIdx.x;  // grid sized exactly, no guard
  float4 v = ((const float4*)s)[i];
  bf16x4 o;
  o[0] = (bf16_t)v.x; o[1] = (bf16_t)v.y; o[2] = (bf16_t)v.z; o[3] = (bf16_t)v.w;
  ((bf16x4*)dvec)[i] = o;
}

// ---------------------------------------------------------------- GEMM ----
// C[m,f] = sum_k A[m,k] * Bw[f,k]  ("B^T" GEMM). 256x256 tile, BK=64,
// 8 waves (2M x 4N), per-wave 128x64. m230-style MINIMUM 2-phase K-loop:
// per tile {STAGE next tile -> other buf; ds_read + MFMA quadrants with NO
// intra-tile barriers (compiler interleaves via counted lgkmcnt); vmcnt(0);
// s_barrier}. One barrier per K-tile. T2 chunk-swizzled LDS; T1 XCD-bijective
// chunks, row-major within chunk.
// EPI 0: QKV epilogue -> scatter q(scaled)/k/vT bf16.  EPI 1: proj epilogue.
template <int EPI, int NCOL>
__global__ __launch_bounds__(512, 2) void gemm256(
    const bf16_t* __restrict__ A, const bf16_t* __restrict__ Bw, int K,
    bf16_t* __restrict__ qo, bf16_t* __restrict__ ko, bf16_t* __restrict__ vto,
    float* __restrict__ yout, const float* __restrict__ bias,
    const int* __restrict__ em) {
  __shared__ bf16_t lds[2][32768];  // per buf: A 32KB + B 32KB (chunk-swizzled)
  const int tid = threadIdx.x;
  const int lane = tid & 63, w = tid >> 6;
  const int wm = w >> 2, wn = w & 3;
  const int g = lane >> 4, c16 = lane & 15;

  // XCD-bijective swizzle (nwg % 8 == 0), row-major within each XCD chunk
  const int nwg = gridDim.x;
  const int lb = ((int)blockIdx.x & 7) * (nwg >> 3) + ((int)blockIdx.x >> 3);
  const int rowbase = (lb / NCOL) * 256;
  const int colbase = (lb % NCOL) * 256;

  // staging: thread stages 8x16B chunks/K-tile; linear LDS dest, inverse-
  // swizzled global source (chunk col = (tid&7) ^ (row&7); rule #21).
  const int trow = tid >> 3;
  const int scol = (((tid & 7) ^ (trow & 7)) << 3);
  const bf16_t* pa = A + (size_t)(rowbase + trow) * K + scol;
  const bf16_t* pb = Bw + (size_t)(colbase + trow) * K + scol;

#define STAGE(j, koff, dst)                                       \
  GLOAD_LDS16(((j) < 4 ? pa + (size_t)((j) * 64) * K              \
                       : pb + (size_t)(((j) - 4) * 64) * K) +     \
                  (koff),                                         \
              (dst) + ((j) * 512 + tid) * 8)

  // swizzled fragment read: row R, k-chunk (kk*4+g), elem = R*64 + swz*8
#define LDFRAG(base, R, kk)            \
  (*(const bf16x8*)((base) + (size_t)(R) * 64 + \
                    (((((kk) << 2) + g) ^ (c16 & 7)) << 3)))

  f32x4 acc[8][4] = {};

  // prologue: stage K-tile 0, drain, publish
#pragma unroll
  for (int j = 0; j < 8; ++j) STAGE(j, 0, (bf16_t*)lds[0]);
  asm volatile("s_waitcnt vmcnt(0)" ::: "memory");
  __builtin_amdgcn_s_barrier();

  const int NT = K >> 6;
  for (int t = 0; t < NT; ++t) {
    const bf16_t* Lb = lds[t & 1];
    const bf16_t* LbB = Lb + 16384;
    const bool pf = (t + 1) < NT;

    // issue next-tile staging FIRST (lands during this tile's compute)
    if (pf) {
      bf16_t* Sd = (bf16_t*)lds[(t + 1) & 1];
      const int koff = (t + 1) << 6;
#pragma unroll
      for (int j = 0; j < 8; ++j) STAGE(j, koff, Sd);
    }

    // quadrant compute, no intra-tile barriers: compiler interleaves
    // ds_read (counted lgkmcnt) with MFMA.
    bf16x8 af[4][2], af2[4][2], b0[2][2], b1[2][2];
#pragma unroll
    for (int mi = 0; mi < 4; ++mi)
#pragma unroll
      for (int kk = 0; kk < 2; ++kk)
        af[mi][kk] = LDFRAG(Lb, wm * 128 + mi * 16 + c16, kk);
#pragma unroll
    for (int ni = 0; ni < 2; ++ni)
#pragma unroll
      for (int kk = 0; kk < 2; ++kk)
        b0[ni][kk] = LDFRAG(LbB, wn * 64 + ni * 16 + c16, kk);
#pragma unroll
    for (int mi = 0; mi < 4; ++mi)
#pragma unroll
      for (int ni = 0; ni < 2; ++ni)
#pragma unroll
        for (int kk = 0; kk < 2; ++kk)
          acc[mi][ni] = MFMA16(af[mi][kk], b0[ni][kk], acc[mi][ni]);

#pragma unroll
    for (int ni = 0; ni < 2; ++ni)
#pragma unroll
      for (int kk = 0; kk < 2; ++kk)
        b1[ni][kk] = LDFRAG(LbB, wn * 64 + (ni + 2) * 16 + c16, kk);
#pragma unroll
    for (int mi = 0; mi < 4; ++mi)
#pragma unroll
      for (int ni = 0; ni < 2; ++ni)
#pragma unroll
        for (int kk = 0; kk < 2; ++kk)
          acc[mi][ni + 2] = MFMA16(af[mi][kk], b1[ni][kk], acc[mi][ni + 2]);

#pragma unroll
    for (int mi = 0; mi < 4; ++mi)
#pragma unroll
      for (int kk = 0; kk < 2; ++kk)
        af2[mi][kk] = LDFRAG(Lb, wm * 128 + (mi + 4) * 16 + c16, kk);
#pragma unroll
    for (int mi = 0; mi < 4; ++mi)
#pragma unroll
      for (int ni = 0; ni < 2; ++ni)
#pragma unroll
        for (int kk = 0; kk < 2; ++kk)
          acc[mi + 4][ni] = MFMA16(af2[mi][kk], b0[ni][kk], acc[mi + 4][ni]);

#pragma unroll
    for (int mi = 0; mi < 4; ++mi)
#pragma unroll
      for (int ni = 0; ni < 2; ++ni)
#pragma unroll
        for (int kk = 0; kk < 2; ++kk)
          acc[mi + 4][ni + 2] = MFMA16(af2[mi][kk], b1[ni][kk], acc[mi + 4][ni + 2]);

    // next tile's loads had the whole compute phase (~2.5k cyc) to land
    if (pf) asm volatile("s_waitcnt vmcnt(0)" ::: "memory");
    __builtin_amdgcn_s_barrier();
  }

  // C/D layout: col = lane&15, row = (lane>>4)*4 + reg  [m89/m91 verified]
  if constexpr (EPI == 0) {
    const int s = colbase >> 10;  // 0=q,1=k,2=v (uniform per block: 256|1024)
#pragma unroll
    for (int mi = 0; mi < 8; ++mi)
#pragma unroll
      for (int ni = 0; ni < 4; ++ni)
#pragma unroll
        for (int j = 0; j < 4; ++j) {
          const int row = rowbase + wm * 128 + mi * 16 + g * 4 + j;  // token
          const int col = colbase + wn * 64 + ni * 16 + c16;         // f
          const float v = acc[mi][ni][j];
          const int bb = row >> 10, n = row & 1023;
          const int h = (col >> 6) & 15, e = col & 63;
          const size_t bh = (size_t)(bb * 16 + h);
          if (s == 0)
            qo[(bh * 1024 + n) * 64 + e] = (bf16_t)(v * QSCALE);
          else if (s == 1)
            ko[(bh * 1024 + n) * 64 + e] = (bf16_t)v;
          else
            vto[(bh * 64 + e) * 1024 + n] = (bf16_t)v;  // V transposed
        }
  } else {
#pragma unroll
    for (int mi = 0; mi < 8; ++mi)
#pragma unroll
      for (int j = 0; j < 4; ++j) {
        const int row = rowbase + wm * 128 + mi * 16 + g * 4 + j;
        const int dt = 128 << em[row];
#pragma unroll
        for (int ni = 0; ni < 4; ++ni) {
          const int col = colbase + wn * 64 + ni * 16 + c16;
          const float v = acc[mi][ni][j] + bias[col];
          yout[(size_t)row * 1024 + col] = (col < dt) ? v : 0.f;
        }
      }
  }
#undef STAGE
#undef LDFRAG
}

// ----------------------------------------------------------- attention ----
// 8 waves x 32 q-rows = 256 q rows / block. KVBLK=64 double-buffered in LDS
// (K row-major [64key][64d], V^T [64d][64key], both XOR-swizzled).
// Swapped QK^T: S = mfma32(Kfrag, Qfrag) -> lane holds P-row slice for
// q = lane&31 in registers; softmax fully in-register; P->bf16 via
// cvt_pk + permlane32_swap feeds PV's A operand directly.
__global__ __launch_bounds__(512, 2) void attn256(
    const bf16_t* __restrict__ Q, const bf16_t* __restrict__ Kb,
    const bf16_t* __restrict__ VT, bf16_t* __restrict__ X) {
  __shared__ bf16_t Klds[2][4096];
  __shared__ bf16_t Vlds[2][4096];
  const int tid = threadIdx.x;
  const int w = tid >> 6, lane = tid & 63;
  const int k32 = lane & 31, q5 = lane >> 5;
  const int bh = blockIdx.y;
  const int qbase = blockIdx.x * 256 + w * 32;

  const bf16_t* Qbh = Q + (size_t)bh * 65536;
  const bf16_t* Kbh = Kb + (size_t)bh * 65536;
  const bf16_t* Vbh = VT + (size_t)bh * 65536;

  const int trow = tid >> 3;
  const int tslot = (tid & 7) ^ (trow & 7);
  const bf16_t* kg = Kbh + (size_t)trow * 64 + tslot * 8;
  const bf16_t* vg = Vbh + (size_t)trow * 1024 + tslot * 8;

  bf16x8 qf[4];
#pragma unroll
  for (int kc = 0; kc < 4; ++kc)
    qf[kc] = *(const bf16x8*)(Qbh + (size_t)(qbase + k32) * 64 + kc * 16 + q5 * 8);
  asm volatile("" ::"v"(qf[0]), "v"(qf[1]), "v"(qf[2]), "v"(qf[3]));

  const int rbase = k32 * 128 + q5 * 16;
  const int rswz = (k32 & 7) << 4;

  f32x16 O0 = {}, O1 = {};
  float m = -3.0e38f, lsum = 0.f;

  GLOAD_LDS16(kg, (bf16_t*)Klds[0] + tid * 8);
  GLOAD_LDS16(vg, (bf16_t*)Vlds[0] + tid * 8);

  for (int step = 0; step < 16; ++step) {
    const int buf = step & 1;
    if (step < 15) {
      GLOAD_LDS16(kg + (step + 1) * 4096, (bf16_t*)Klds[buf ^ 1] + tid * 8);
      GLOAD_LDS16(vg + (step + 1) * 64, (bf16_t*)Vlds[buf ^ 1] + tid * 8);
      asm volatile("s_waitcnt vmcnt(2)" ::: "memory");
    } else {
      asm volatile("s_waitcnt vmcnt(0)" ::: "memory");
    }
    __builtin_amdgcn_s_barrier();

    const char* Kl = (const char*)Klds[buf];
    const char* Vl = (const char*)Vlds[buf];

    f32x16 S0 = {}, S1 = {};
#pragma unroll
    for (int kc = 0; kc < 4; ++kc) {
      const int off = (rbase + kc * 32) ^ rswz;
      bf16x8 kf0 = *(const bf16x8*)(Kl + off);
      bf16x8 kf1 = *(const bf16x8*)(Kl + off + 4096);
      S0 = MFMA32(kf0, qf[kc], S0);
      S1 = MFMA32(kf1, qf[kc], S1);
    }

    float pm = fmaxf(S0[0], S1[0]);
#pragma unroll
    for (int r = 1; r < 16; ++r) pm = fmaxf(pm, fmaxf(S0[r], S1[r]));
    pm = fmaxf(pm, __shfl_xor(pm, 32));
    if (__any(pm > m + 8.f)) {           // defer-max, THR=8 (log2 domain)
      const float mnew = fmaxf(m, pm);
      const float corr = __builtin_amdgcn_exp2f(m - mnew);
      m = mnew;
      lsum *= corr;
      const int ci = __builtin_bit_cast(int, corr);
#pragma unroll
      for (int r = 0; r < 16; ++r) {
        const int qsel = (r & 3) + 8 * (r >> 2) + 4 * q5;
        const float cr = __builtin_bit_cast(
            float, __builtin_amdgcn_ds_bpermute(qsel << 2, ci));
        O0[r] *= cr;
        O1[r] *= cr;
      }
    }
    float ps = 0.f;
#pragma unroll
    for (int r = 0; r < 16; ++r) {
      float p = __builtin_amdgcn_exp2f(S0[r] - m);
      ps += p; S0[r] = p;
      p = __builtin_amdgcn_exp2f(S1[r] - m);
      ps += p; S1[r] = p;
    }
    lsum += ps;

#define MAKE_PA(PV, B0, PA)                            \
  {                                                    \
    unsigned a_ = cvtpk(PV[B0 + 0], PV[B0 + 1]);       \
    unsigned b_ = cvtpk(PV[B0 + 2], PV[B0 + 3]);       \
    unsigned c_ = cvtpk(PV[B0 + 4], PV[B0 + 5]);       \
    unsigned d_ = cvtpk(PV[B0 + 6], PV[B0 + 7]);       \
    pl32swap(a_, c_);                                  \
    pl32swap(b_, d_);                                  \
    i32x4 wv_;                                         \
    wv_[0] = a_; wv_[1] = b_; wv_[2] = c_; wv_[3] = d_; \
    PA = __builtin_bit_cast(bf16x8, wv_);              \
  }
#define PV_STEP(PV, B0, KS)                                       \
  {                                                               \
    bf16x8 pa;                                                    \
    MAKE_PA(PV, B0, pa);                                          \
    const int voff = (rbase + (KS) * 32) ^ rswz;                  \
    bf16x8 vf0 = *(const bf16x8*)(Vl + voff);                     \
    bf16x8 vf1 = *(const bf16x8*)(Vl + voff + 4096);              \
    O0 = MFMA32(pa, vf0, O0);                                     \
    O1 = MFMA32(pa, vf1, O1);                                     \
  }
    PV_STEP(S0, 0, 0)
    PV_STEP(S0, 8, 1)
    PV_STEP(S1, 0, 2)
    PV_STEP(S1, 8, 3)

    __builtin_amdgcn_s_barrier();
  }

  lsum += __shfl_xor(lsum, 32);
  const float rinv = 1.f / lsum;
  const int ri = __builtin_bit_cast(int, rinv);
  const int bb = bh >> 4, h = bh & 15;
  bf16_t* Xb = X + (size_t)bb * 1024 * 1024 + h * 64;
#pragma unroll
  for (int r = 0; r < 16; ++r) {
    const int qsel = (r & 3) + 8 * (r >> 2) + 4 * q5;
    const float rv = __builtin_bit_cast(
        float, __builtin_amdgcn_ds_bpermute(qsel << 2, ri));
    const size_t rowoff = (size_t)(qbase + qsel) * 1024;
    Xb[rowoff + k32] = (bf16_t)(O0[r] * rv);
    Xb[rowoff + 32 + k32] = (bf16_t)(O1[r] * rv);
  }
}

// --------------------------------------------------------------- launch ----
extern "C" void kernel_launch(void* const* d_in, const int* in_sizes, int n_in,
                              void* d_out, int out_size, void* d_ws,
                              size_t ws_size, hipStream_t stream) {
  const float* x = (const float*)d_in[0];
  const int* em = (const int*)d_in[1];
  const float* qkvw = (const float*)d_in[2];
  const float* projw = (const float*)d_in[3];
  const float* projb = (const float*)d_in[4];
  float* out = (float*)d_out;

  char* ws = (char*)d_ws;
  size_t off = 0;
  bf16_t* xin = (bf16_t*)(ws + off); off += (size_t)16384 * 1024 * 2;  // reused as Xattn
  bf16_t* wq  = (bf16_t*)(ws + off); off += (size_t)3072 * 1024 * 2;
  bf16_t* wp  = (bf16_t*)(ws + off); off += (size_t)1024 * 1024 * 2;
  bf16_t* Qb  = (bf16_t*)(ws + off); off += (size_t)256 * 1024 * 64 * 2;
  bf16_t* Kb  = (bf16_t*)(ws + off); off += (size_t)256 * 1024 * 64 * 2;
  bf16_t* VTb = (bf16_t*)(ws + off); off += (size_t)256 * 64 * 1024 * 2;

  prep_tokens<<<16384, 256, 0, stream>>>(x, em, xin);
  conv_w<<<3072, 256, 0, stream>>>(qkvw, wq);
  conv_w<<<1024, 256, 0, stream>>>(projw, wp);

  // QKV: M=16384, N=3072, K=1024 -> 64x12 = 768 blocks
  gemm256<0, 12><<<768, 512, 0, stream>>>(
      xin, wq, 1024, Qb, Kb, VTb, nullptr, nullptr, nullptr);

  // attention: 4 q-tiles x 256 (b,h); writes Xattn into xin region
  attn256<<<dim3(4, 256), 512, 0, stream>>>(Qb, Kb, VTb, xin);

  // proj: M=16384, N=1024, K=1024 -> 64x4 = 256 blocks
  gemm256<1, 4><<<256, 512, 0, stream>>>(
      xin, wp, 1024, nullptr, nullptr, nullptr, out, projb, em);
}